// Round 6
// baseline (49.577 us; speedup 1.0000x reference)
//
#include <hip/hip_runtime.h>

// ShiftDisLoss: per-box BEV corner distance loss, weighted global sum / B.
// Inputs: pred_bbox3d [B,N,7] f32, gt_bbox3d [B,N,7] f32, weights [B,N] f32.
// Output: 1 f32 scalar. B=4, N=1e6.
//
// R5 -> R6: 3-deep prefetch, 5 LDS buffers, ONE barrier per tile.
// TILE=256 (16 chunks of 1 KB: 7 pred + 7 gt + 1 weights + 1 dummy; 4 per
// wave). Steady state: stage tile t+3 while computing tile t, then
// s_waitcnt vmcnt(12) -- 12 chunks (t+1..t+3) stay in flight across the
// barrier; memory never drains. Race-free: NBUF(5) >= DEPTH(3)+2, so the
// buffer staged at iter t was last read at iter t-2, guaranteed complete by
// the single collective barrier at iter t-1. 2 blocks/CU (77 KB LDS each).

#define BLOCK 256
#define TILE 256                 // boxes per tile
#define NBUF 5
#define NBLOCKS 512              // persistent grid: 2 blocks/CU
#define TILE_F 1792              // TILE*7 floats per tensor tile
#define TILE_F4 448              // TILE*7/4 float4 per tensor tile

typedef __attribute__((address_space(1))) const void gas_void;
typedef __attribute__((address_space(3))) void las_void;

__device__ __forceinline__ float fast_rcp(float x) {
    return __builtin_amdgcn_rcpf(x);
}

struct SC { float x0, y0, x1, y1, x2, y2, x3, y3; };

// Algebraic replacement of the reference's corner argsort (see R2): corners
// are c+-u, c+-v; dist^2 keys are |c|^2+|u|^2 +- 2c.u / 2c.v, so ordering
// reduces to sign/magnitude selection on t0=c.u, t1=c.v; the mid-pair x^2
// re-sort reduces to sign(cx*qx).
__device__ __forceinline__ SC sorted_corners(float cx, float cy,
                                             float dx, float dy, float h) {
    float s = __sinf(h), c = __cosf(h);
    float hx = 0.5f * dx, hy = 0.5f * dy;
    float ux = hx * c - hy * s, uy = hx * s + hy * c;
    float vx = hx * c + hy * s, vy = hx * s - hy * c;
    float t0 = cx * ux + cy * uy;
    float t1 = cx * vx + cy * vy;
    bool umajor = fabsf(t0) >= fabsf(t1);
    float px = umajor ? ux : vx, py = umajor ? uy : vy;
    float tp = umajor ? t0 : t1;
    float qx = umajor ? vx : ux, qy = umajor ? vy : uy;
    float sp = copysignf(1.0f, tp);
    float sm = copysignf(1.0f, cx * qx);
    SC r;
    r.x0 = cx - sp * px; r.y0 = cy - sp * py;   // nearest
    r.x1 = cx - sm * qx; r.y1 = cy - sm * qy;   // mid (smaller x^2)
    r.x2 = cx + sm * qx; r.y2 = cy + sm * qy;   // mid (larger x^2)
    r.x3 = cx + sp * px; r.y3 = cy + sp * py;   // farthest
    return r;
}

__device__ __forceinline__ float box_loss(float pcx, float pcy, float pdx,
                                          float pdy, float ph,
                                          float gcx, float gcy, float gdx,
                                          float gdy, float gh) {
    SC p = sorted_corners(pcx, pcy, pdx, pdy, ph);
    SC g = sorted_corners(gcx, gcy, gdx, gdy, gh);
    float d1x = g.x1 - g.x0, d1y = g.y1 - g.y0;
    float d2x = g.x2 - g.x0, d2y = g.y2 - g.y0;
    float d3x = g.x3 - g.x0, d3y = g.y3 - g.y0;
    float n1 = d1x * (p.y1 - g.y0) - d1y * (p.x1 - g.x0);
    float n2 = d2x * (p.y2 - g.y0) - d2y * (p.x2 - g.x0);
    float n3 = d3x * (p.y0 - g.y0) - d3y * (p.x0 - g.x0);
    float gx = g.x1 - g.x2, gy = g.y1 - g.y2;
    float diag = gx * gx + gy * gy;
    float sum = n1 * n1 * fast_rcp(d1x * d1x + d1y * d1y)
              + n2 * n2 * fast_rcp(d2x * d2x + d2y * d2y)
              + n3 * n3 * fast_rcp(d3x * d3x + d3y * d3y);
    return sum * fast_rcp(diag);
}

__global__ __launch_bounds__(BLOCK, 2)
void shiftdis_loss_kernel(const float* __restrict__ pred,
                          const float* __restrict__ gt,
                          const float* __restrict__ w,
                          float* __restrict__ out,
                          long long n_boxes, float inv_b) {
    __shared__ float sP[NBUF][TILE_F];   // 5 x 7168 B
    __shared__ float sG[NBUF][TILE_F];   // 5 x 7168 B
    __shared__ float sW[NBUF][TILE];     // 5 x 1024 B
    __shared__ float sScratch[256];      // dummy landing (never read)
    __shared__ float wsum[4];

    const int tid = threadIdx.x;
    const int wid = tid >> 6;
    const int lane = tid & 63;

    const float4* predF4 = reinterpret_cast<const float4*>(pred);
    const float4* gtF4 = reinterpret_cast<const float4*>(gt);
    const float4* wF4 = reinterpret_cast<const float4*>(w);

    const long long nfull = n_boxes / TILE;   // full tiles
    const int G = gridDim.x;
    const long long bid = blockIdx.x;

    float acc = 0.0f;

    // Stage one tile into LDS buffer `buf`. 16 chunks of 64 float4 (1 KB):
    // 7 pred + 7 gt + 1 weights + 1 dummy, 4 per wave => uniform vmcnt.
    auto STAGE = [&](int buf, long long t) {
        const long long boxF4 = t * (long long)TILE_F4;
        const long long wbF4 = t * (long long)(TILE / 4);
#pragma unroll
        for (int k = 0; k < 4; ++k) {
            int c = wid * 4 + k;                 // 0..15 chunk id
            const float4* src;
            float* dst;
            if (c < 7) {
                src = predF4 + boxF4 + c * 64 + lane;
                dst = sP[buf] + c * 256;
            } else if (c < 14) {
                src = gtF4 + boxF4 + (c - 7) * 64 + lane;
                dst = sG[buf] + (c - 7) * 256;
            } else if (c == 14) {
                src = wF4 + wbF4 + lane;
                dst = sW[buf];
            } else {
                src = wF4 + wbF4 + lane;         // benign duplicate read
                dst = sScratch;
            }
            __builtin_amdgcn_global_load_lds((gas_void*)src, (las_void*)dst,
                                             16, 0, 0);
        }
    };

    // number of tiles owned by this block
    long long nt = 0;
    if (bid < nfull) nt = (nfull - bid + G - 1) / G;

    if (nt > 0) {
        // prologue: stage up to 3 tiles ahead
        for (long long i = 0; i < 3 && i < nt; ++i)
            STAGE((int)(i % NBUF), bid + i * G);

        for (long long i = 0; i < nt; ++i) {
            if (i + 3 < nt) {
                STAGE((int)((i + 3) % NBUF), bid + (i + 3) * G);
                asm volatile("s_waitcnt vmcnt(12)" ::: "memory");
            } else if (i + 2 < nt) {
                asm volatile("s_waitcnt vmcnt(8)" ::: "memory");
            } else if (i + 1 < nt) {
                asm volatile("s_waitcnt vmcnt(4)" ::: "memory");
            } else {
                asm volatile("s_waitcnt vmcnt(0)" ::: "memory");
            }
            __builtin_amdgcn_sched_barrier(0);
            __builtin_amdgcn_s_barrier();      // tile i visible; buf i-2 free
            __builtin_amdgcn_sched_barrier(0);

            {
                int buf = (int)(i % NBUF);
                const float* P = sP[buf] + tid * 7;
                const float* Q = sG[buf] + tid * 7;
                float wt = sW[buf][tid];
                acc += box_loss(P[0], P[1], P[3], P[4], P[6],
                                Q[0], Q[1], Q[3], Q[4], Q[6]) * wt;
            }
        }
    }

    // ragged tail (n % TILE boxes), block 0 only, direct from global
    if (bid == 0) {
        for (long long b = nfull * TILE + tid; b < n_boxes; b += BLOCK) {
            const float* p = pred + b * 7;
            const float* q = gt + b * 7;
            acc += box_loss(p[0], p[1], p[3], p[4], p[6],
                            q[0], q[1], q[3], q[4], q[6]) * w[b];
        }
    }

    // wave-64 reduce
#pragma unroll
    for (int off = 32; off > 0; off >>= 1)
        acc += __shfl_down(acc, off, 64);

    if (lane == 0) wsum[wid] = acc;
    __syncthreads();
    if (tid == 0) {
        float bsum = wsum[0] + wsum[1] + wsum[2] + wsum[3];
        atomicAdd(out, bsum * inv_b);
    }
}

extern "C" void kernel_launch(void* const* d_in, const int* in_sizes, int n_in,
                              void* d_out, int out_size, void* d_ws, size_t ws_size,
                              hipStream_t stream) {
    const float* pred = (const float*)d_in[0];
    const float* gt   = (const float*)d_in[1];
    const float* w    = (const float*)d_in[2];
    float* out = (float*)d_out;

    long long n_boxes = (long long)in_sizes[2];   // B*N
    const float inv_b = 0.25f;                    // B = 4

    hipMemsetAsync(d_out, 0, sizeof(float), stream);

    shiftdis_loss_kernel<<<NBLOCKS, BLOCK, 0, stream>>>(pred, gt, w, out,
                                                        n_boxes, inv_b);
}

// Round 7
// 47.631 us; speedup vs baseline: 1.0408x; 1.0408x over previous
//
#include <hip/hip_runtime.h>

// ShiftDisLoss: per-box BEV corner distance loss, weighted global sum / B.
// Inputs: pred_bbox3d [B,N,7] f32, gt_bbox3d [B,N,7] f32, weights [B,N] f32.
// Output: 1 f32 scalar. B=4, N=1e6.
//
// R6 -> R7: wave-private pipelines, ZERO barriers in the main loop.
// Each wave owns 256-box tiles (7 pred + 7 gt + 1 weight chunks = 15
// global_load_lds of 1 KB each -- exactly integral) and double-buffers its
// own 15 KB LDS region. global_load_lds completion is per-wave vmcnt, so
// tile readiness needs only s_waitcnt vmcnt(15) (next tile stays in flight)
// -- no s_barrier, no inter-wave lockstep. 4 boxes/thread ILP. LDS
// 4 waves x 2 x 15360 B = 120 KB -> 1 block/CU, grid = 256 blocks.

#define BLOCK 256
#define WTILE 256                // boxes per wave-tile
#define NBLOCKS 256              // 1 block/CU
#define WBUF_F 3840              // floats per wave buffer (pred|gt|w)
#define PRED_OFF 0
#define GT_OFF 1792
#define W_OFF 3584

typedef __attribute__((address_space(1))) const void gas_void;
typedef __attribute__((address_space(3))) void las_void;

__device__ __forceinline__ float fast_rcp(float x) {
    return __builtin_amdgcn_rcpf(x);
}

struct SC { float x0, y0, x1, y1, x2, y2, x3, y3; };

// Algebraic replacement of the reference's corner argsort (see R2): corners
// are c+-u, c+-v; dist^2 keys are |c|^2+|u|^2 +- 2c.u / 2c.v, so ordering
// reduces to sign/magnitude selection on t0=c.u, t1=c.v; the mid-pair x^2
// re-sort reduces to sign(cx*qx).
__device__ __forceinline__ SC sorted_corners(float cx, float cy,
                                             float dx, float dy, float h) {
    float s = __sinf(h), c = __cosf(h);
    float hx = 0.5f * dx, hy = 0.5f * dy;
    float ux = hx * c - hy * s, uy = hx * s + hy * c;
    float vx = hx * c + hy * s, vy = hx * s - hy * c;
    float t0 = cx * ux + cy * uy;
    float t1 = cx * vx + cy * vy;
    bool umajor = fabsf(t0) >= fabsf(t1);
    float px = umajor ? ux : vx, py = umajor ? uy : vy;
    float tp = umajor ? t0 : t1;
    float qx = umajor ? vx : ux, qy = umajor ? vy : uy;
    float sp = copysignf(1.0f, tp);
    float sm = copysignf(1.0f, cx * qx);
    SC r;
    r.x0 = cx - sp * px; r.y0 = cy - sp * py;   // nearest
    r.x1 = cx - sm * qx; r.y1 = cy - sm * qy;   // mid (smaller x^2)
    r.x2 = cx + sm * qx; r.y2 = cy + sm * qy;   // mid (larger x^2)
    r.x3 = cx + sp * px; r.y3 = cy + sp * py;   // farthest
    return r;
}

__device__ __forceinline__ float box_loss(float pcx, float pcy, float pdx,
                                          float pdy, float ph,
                                          float gcx, float gcy, float gdx,
                                          float gdy, float gh) {
    SC p = sorted_corners(pcx, pcy, pdx, pdy, ph);
    SC g = sorted_corners(gcx, gcy, gdx, gdy, gh);
    float d1x = g.x1 - g.x0, d1y = g.y1 - g.y0;
    float d2x = g.x2 - g.x0, d2y = g.y2 - g.y0;
    float d3x = g.x3 - g.x0, d3y = g.y3 - g.y0;
    float n1 = d1x * (p.y1 - g.y0) - d1y * (p.x1 - g.x0);
    float n2 = d2x * (p.y2 - g.y0) - d2y * (p.x2 - g.x0);
    float n3 = d3x * (p.y0 - g.y0) - d3y * (p.x0 - g.x0);
    float gx = g.x1 - g.x2, gy = g.y1 - g.y2;
    float diag = gx * gx + gy * gy;
    float sum = n1 * n1 * fast_rcp(d1x * d1x + d1y * d1y)
              + n2 * n2 * fast_rcp(d2x * d2x + d2y * d2y)
              + n3 * n3 * fast_rcp(d3x * d3x + d3y * d3y);
    return sum * fast_rcp(diag);
}

__global__ __launch_bounds__(BLOCK, 1)
void shiftdis_loss_kernel(const float* __restrict__ pred,
                          const float* __restrict__ gt,
                          const float* __restrict__ w,
                          float* __restrict__ out,
                          long long n_boxes, float inv_b) {
    __shared__ float sBuf[4][2][WBUF_F];   // per-wave double buffers, 120 KB
    __shared__ float wsum[4];

    const int tid = threadIdx.x;
    const int wid = tid >> 6;
    const int lane = tid & 63;

    const float4* predF4 = reinterpret_cast<const float4*>(pred);
    const float4* gtF4 = reinterpret_cast<const float4*>(gt);
    const float4* wF4 = reinterpret_cast<const float4*>(w);

    const long long nfull = n_boxes / WTILE;       // full wave-tiles
    const long long totalWaves = (long long)gridDim.x * 4;
    const long long wv = (long long)blockIdx.x * 4 + wid;

    float acc = 0.0f;

    // Stage one 256-box tile into this wave's LDS buffer `buf`:
    // 7 pred chunks + 7 gt chunks + 1 weight chunk, 1 KB each (15 loads).
    auto STAGE = [&](int buf, long long t) {
        const long long f4 = t * 448;              // 256*7/4 float4 per tensor
        float* base = sBuf[wid][buf];
#pragma unroll
        for (int k = 0; k < 7; ++k) {
            __builtin_amdgcn_global_load_lds(
                (gas_void*)(predF4 + f4 + k * 64 + lane),
                (las_void*)(base + PRED_OFF + k * 256), 16, 0, 0);
            __builtin_amdgcn_global_load_lds(
                (gas_void*)(gtF4 + f4 + k * 64 + lane),
                (las_void*)(base + GT_OFF + k * 256), 16, 0, 0);
        }
        __builtin_amdgcn_global_load_lds(
            (gas_void*)(wF4 + t * 64 + lane),
            (las_void*)(base + W_OFF), 16, 0, 0);
    };

    long long nt = 0;
    if (wv < nfull) nt = (nfull - wv + totalWaves - 1) / totalWaves;

    if (nt > 0) {
        STAGE(0, wv);
        int cur = 0;
        for (long long i = 0; i < nt; ++i) {
            if (i + 1 < nt) {
                STAGE(cur ^ 1, wv + (i + 1) * totalWaves);
                // own 15 cur-tile loads retired; next 15 stay in flight
                asm volatile("s_waitcnt vmcnt(15)" ::: "memory");
            } else {
                asm volatile("s_waitcnt vmcnt(0)" ::: "memory");
            }
            __builtin_amdgcn_sched_barrier(0);

            const float* base = sBuf[wid][cur];
#pragma unroll
            for (int j = 0; j < 4; ++j) {
                int b = lane + j * 64;             // 7-word lane stride: CF
                const float* P = base + PRED_OFF + b * 7;
                const float* Q = base + GT_OFF + b * 7;
                float wt = base[W_OFF + b];
                acc += box_loss(P[0], P[1], P[3], P[4], P[6],
                                Q[0], Q[1], Q[3], Q[4], Q[6]) * wt;
            }
            // all ds_reads of `cur` are consumed into acc above, so their
            // waitcnts have retired before the next STAGE can overwrite cur
            __builtin_amdgcn_sched_barrier(0);
            cur ^= 1;
        }
    }

    // ragged tail (n % WTILE boxes), block 0 only, direct from global
    if (blockIdx.x == 0) {
        for (long long b = nfull * WTILE + tid; b < n_boxes; b += BLOCK) {
            const float* p = pred + b * 7;
            const float* q = gt + b * 7;
            acc += box_loss(p[0], p[1], p[3], p[4], p[6],
                            q[0], q[1], q[3], q[4], q[6]) * w[b];
        }
    }

    // wave-64 reduce
#pragma unroll
    for (int off = 32; off > 0; off >>= 1)
        acc += __shfl_down(acc, off, 64);

    if (lane == 0) wsum[wid] = acc;
    __syncthreads();
    if (tid == 0) {
        float bsum = wsum[0] + wsum[1] + wsum[2] + wsum[3];
        atomicAdd(out, bsum * inv_b);
    }
}

extern "C" void kernel_launch(void* const* d_in, const int* in_sizes, int n_in,
                              void* d_out, int out_size, void* d_ws, size_t ws_size,
                              hipStream_t stream) {
    const float* pred = (const float*)d_in[0];
    const float* gt   = (const float*)d_in[1];
    const float* w    = (const float*)d_in[2];
    float* out = (float*)d_out;

    long long n_boxes = (long long)in_sizes[2];   // B*N
    const float inv_b = 0.25f;                    // B = 4

    hipMemsetAsync(d_out, 0, sizeof(float), stream);

    shiftdis_loss_kernel<<<NBLOCKS, BLOCK, 0, stream>>>(pred, gt, w, out,
                                                        n_boxes, inv_b);
}

// Round 8
// 43.777 us; speedup vs baseline: 1.1325x; 1.0880x over previous
//
#include <hip/hip_runtime.h>

// ShiftDisLoss: per-box BEV corner distance loss, weighted global sum / B.
// Inputs: pred_bbox3d [B,N,7] f32, gt_bbox3d [B,N,7] f32, weights [B,N] f32.
// Output: 1 f32 scalar. B=4, N=1e6.
//
// FINAL (revert to R4, the measured optimum): persistent double-buffered
// pipeline. 512 blocks (2/CU), each grid-strides over 512-box tiles. Tile
// t+1 is staged into the alternate LDS buffer via global_load_lds (8 chunks
// per wave, incl. weights) BEFORE computing tile t; raw s_barrier + counted
// s_waitcnt vmcnt(8) keeps the prefetch in flight across barriers (no
// vmcnt(0) drain in the main loop). Measured 44.6 us = 5.3 TB/s payload
// (~84% of the 6.3 TB/s copy ceiling). R5 (5 blk/CU), R6 (depth-3, single
// barrier), R7 (wave-private, barrier-free) all regressed: the binding
// resource is per-tile compute window x resident pipelines, not occupancy,
// depth, or barrier count.

#define BLOCK 256
#define TILE 512                 // boxes per tile
#define NBLOCKS 512              // persistent grid: 2 blocks/CU
#define TILE_F 3584              // TILE*7 floats per tensor tile
#define TILE_F4 896              // TILE*7/4 float4 per tensor tile

typedef __attribute__((address_space(1))) const void gas_void;
typedef __attribute__((address_space(3))) void las_void;

__device__ __forceinline__ float fast_rcp(float x) {
    return __builtin_amdgcn_rcpf(x);
}

struct SC { float x0, y0, x1, y1, x2, y2, x3, y3; };

// Algebraic replacement of the reference's corner argsort (see R2): corners
// are c+-u, c+-v; dist^2 keys are |c|^2+|u|^2 +- 2c.u / 2c.v, so ordering
// reduces to sign/magnitude selection on t0=c.u, t1=c.v; the mid-pair x^2
// re-sort reduces to sign(cx*qx).
__device__ __forceinline__ SC sorted_corners(float cx, float cy,
                                             float dx, float dy, float h) {
    float s = __sinf(h), c = __cosf(h);
    float hx = 0.5f * dx, hy = 0.5f * dy;
    float ux = hx * c - hy * s, uy = hx * s + hy * c;
    float vx = hx * c + hy * s, vy = hx * s - hy * c;
    float t0 = cx * ux + cy * uy;
    float t1 = cx * vx + cy * vy;
    bool umajor = fabsf(t0) >= fabsf(t1);
    float px = umajor ? ux : vx, py = umajor ? uy : vy;
    float tp = umajor ? t0 : t1;
    float qx = umajor ? vx : ux, qy = umajor ? vy : uy;
    float sp = copysignf(1.0f, tp);
    float sm = copysignf(1.0f, cx * qx);
    SC r;
    r.x0 = cx - sp * px; r.y0 = cy - sp * py;   // nearest
    r.x1 = cx - sm * qx; r.y1 = cy - sm * qy;   // mid (smaller x^2)
    r.x2 = cx + sm * qx; r.y2 = cy + sm * qy;   // mid (larger x^2)
    r.x3 = cx + sp * px; r.y3 = cy + sp * py;   // farthest
    return r;
}

__device__ __forceinline__ float box_loss(float pcx, float pcy, float pdx,
                                          float pdy, float ph,
                                          float gcx, float gcy, float gdx,
                                          float gdy, float gh) {
    SC p = sorted_corners(pcx, pcy, pdx, pdy, ph);
    SC g = sorted_corners(gcx, gcy, gdx, gdy, gh);
    float d1x = g.x1 - g.x0, d1y = g.y1 - g.y0;
    float d2x = g.x2 - g.x0, d2y = g.y2 - g.y0;
    float d3x = g.x3 - g.x0, d3y = g.y3 - g.y0;
    float n1 = d1x * (p.y1 - g.y0) - d1y * (p.x1 - g.x0);
    float n2 = d2x * (p.y2 - g.y0) - d2y * (p.x2 - g.x0);
    float n3 = d3x * (p.y0 - g.y0) - d3y * (p.x0 - g.x0);
    float gx = g.x1 - g.x2, gy = g.y1 - g.y2;
    float diag = gx * gx + gy * gy;
    float sum = n1 * n1 * fast_rcp(d1x * d1x + d1y * d1y)
              + n2 * n2 * fast_rcp(d2x * d2x + d2y * d2y)
              + n3 * n3 * fast_rcp(d3x * d3x + d3y * d3y);
    return sum * fast_rcp(diag);
}

__global__ __launch_bounds__(BLOCK, 2)
void shiftdis_loss_kernel(const float* __restrict__ pred,
                          const float* __restrict__ gt,
                          const float* __restrict__ w,
                          float* __restrict__ out,
                          long long n_boxes, float inv_b) {
    __shared__ float sP[2][TILE_F];      // 2 x 14336 B
    __shared__ float sG[2][TILE_F];      // 2 x 14336 B
    __shared__ float sW[2][TILE];        // 2 x 2048 B
    __shared__ float sScratch[256];      // dummy landing (never read)
    __shared__ float wsum[4];

    const int tid = threadIdx.x;
    const int wid = tid >> 6;
    const int lane = tid & 63;

    const float4* predF4 = reinterpret_cast<const float4*>(pred);
    const float4* gtF4 = reinterpret_cast<const float4*>(gt);
    const float4* wF4 = reinterpret_cast<const float4*>(w);

    const long long nfull = n_boxes / TILE;   // full tiles
    const int G = gridDim.x;

    float acc = 0.0f;

    // Stage one tile's pred/gt/weights into LDS buffer `buf`.
    // Per wave: 7 box chunks (1 KB each) + 1 weight/dummy chunk = 8
    // global_load_lds => uniform vmcnt accounting across waves.
    auto STAGE = [&](int buf, long long t) {
        const long long boxF4 = t * (long long)TILE_F4;
#pragma unroll
        for (int k = 0; k < 7; ++k) {
            int c = wid * 7 + k;                 // 0..27 unified chunk id
            int isGt = (c >= 14);
            int cc = isGt ? (c - 14) : c;        // 0..13 within tensor
            const float4* src = (isGt ? gtF4 : predF4) + boxF4 + cc * 64 + lane;
            float* dst = (isGt ? sG[buf] : sP[buf]) + cc * 256;
            __builtin_amdgcn_global_load_lds((gas_void*)src, (las_void*)dst,
                                             16, 0, 0);
        }
        {
            const long long wb = t * (long long)(TILE / 4);
            const float4* src = wF4 + wb + (wid & 1) * 64 + lane;
            float* dst = (wid < 2) ? (sW[buf] + wid * 256) : sScratch;
            __builtin_amdgcn_global_load_lds((gas_void*)src, (las_void*)dst,
                                             16, 0, 0);
        }
    };

    if ((long long)blockIdx.x < nfull) {
        STAGE(0, (long long)blockIdx.x);
        int cur = 0;
        for (long long t = blockIdx.x; t < nfull; t += G) {
            long long tn = t + G;
            if (tn < nfull) {
                STAGE(cur ^ 1, tn);
                // own 8 cur-tile loads complete; 8 next-tile loads in flight
                asm volatile("s_waitcnt vmcnt(8)" ::: "memory");
            } else {
                asm volatile("s_waitcnt vmcnt(0)" ::: "memory");
            }
            __builtin_amdgcn_sched_barrier(0);
            __builtin_amdgcn_s_barrier();      // cur tile visible to all waves
            __builtin_amdgcn_sched_barrier(0);

#pragma unroll
            for (int j = 0; j < 2; ++j) {
                int b = tid + j * 256;           // 0..511 within tile
                const float* P = sP[cur] + b * 7;
                const float* Q = sG[cur] + b * 7;
                float wt = sW[cur][b];
                acc += box_loss(P[0], P[1], P[3], P[4], P[6],
                                Q[0], Q[1], Q[3], Q[4], Q[6]) * wt;
            }

            __builtin_amdgcn_sched_barrier(0);
            __builtin_amdgcn_s_barrier();      // all done reading cur buffer
            __builtin_amdgcn_sched_barrier(0);
            cur ^= 1;
        }
    }

    // ragged tail (n % TILE boxes), block 0 only, direct from global
    if (blockIdx.x == 0) {
        for (long long b = nfull * TILE + tid; b < n_boxes; b += BLOCK) {
            const float* p = pred + b * 7;
            const float* q = gt + b * 7;
            acc += box_loss(p[0], p[1], p[3], p[4], p[6],
                            q[0], q[1], q[3], q[4], q[6]) * w[b];
        }
    }

    // wave-64 reduce
#pragma unroll
    for (int off = 32; off > 0; off >>= 1)
        acc += __shfl_down(acc, off, 64);

    if (lane == 0) wsum[wid] = acc;
    __syncthreads();
    if (tid == 0) {
        float bsum = wsum[0] + wsum[1] + wsum[2] + wsum[3];
        atomicAdd(out, bsum * inv_b);
    }
}

extern "C" void kernel_launch(void* const* d_in, const int* in_sizes, int n_in,
                              void* d_out, int out_size, void* d_ws, size_t ws_size,
                              hipStream_t stream) {
    const float* pred = (const float*)d_in[0];
    const float* gt   = (const float*)d_in[1];
    const float* w    = (const float*)d_in[2];
    float* out = (float*)d_out;

    long long n_boxes = (long long)in_sizes[2];   // B*N
    const float inv_b = 0.25f;                    // B = 4

    hipMemsetAsync(d_out, 0, sizeof(float), stream);

    shiftdis_loss_kernel<<<NBLOCKS, BLOCK, 0, stream>>>(pred, gt, w, out,
                                                        n_boxes, inv_b);
}